// Round 3
// baseline (84.891 us; speedup 1.0000x reference)
//
#include <hip/hip_runtime.h>
#include <stdint.h>

typedef _Float16 h2 __attribute__((ext_vector_type(2)));
typedef _Float16 h8 __attribute__((ext_vector_type(8)));
typedef float f32x4 __attribute__((ext_vector_type(4)));
typedef unsigned int u32;
typedef unsigned short u16;

// LDS strides (elements of the buffer's type)
#define CB_STR  72    // cb   [j=64][h]      u16 ; 144B rows (uint4 reads)
#define WA_STR  68    // waT  [n][ho=64][h]  u16 ; 136B rows (uint2 reads)
#define WP_STR  68    // wpT  [n][o=64][h]   u16 ; 136B rows
#define P_STR   68    // P    [n][atom][ho]  u16 ; 136B rows
#define CW_STR  68    // cwT  [n][o=64][j]   u16 ; 136B rows
#define ABF_STR 264   // ab   [i=64][c=(n,j)=256] u16 ; 528B rows (uint4 reads)

__device__ __forceinline__ u32 pk2(float a, float b) {
    return __builtin_bit_cast(u32, __builtin_amdgcn_cvt_pkrtz(a, b));
}
__device__ __forceinline__ h8 frag4(u32 a, u32 b, u32 c, u32 d) {
    return __builtin_bit_cast(h8, make_uint4(a, b, c, d));
}

// One block per molecule, all 4 heads in-block -> every output element computed by
// exactly one block: plain stores, NO memset, single dispatch.
// out[b,i,o] = sum_n sum_j att_n[i,j] * cw_n[j,o],  cw_n = c @ Wp_n  (fused projection)
union SMemU {
    struct { u16 wa[4][64 * WA_STR]; u16 wp[4][64 * WP_STR]; } p1;  // 69,632 B (phase 0-1)
    u16 ab[64 * ABF_STR];                                            // 33,792 B (phase 2-3)
};

__global__ __launch_bounds__(512, 1) void atom_attn(
    const float* __restrict__ inputs,
    const int*   __restrict__ scope,
    const float* __restrict__ Wa_pair,
    const float* __restrict__ Wa_score,
    const float* __restrict__ W_proj,
    float* __restrict__ out_mol,    // [64][64]
    float* __restrict__ out_flat)   // [N+1][64]
{
    __shared__ __align__(16) SMemU s_u;                 // 69,632 B
    __shared__ __align__(16) u16 s_cb[64 * CB_STR];     //  9,216 B
    __shared__ __align__(16) u16 s_p [4][64 * P_STR];   // 34,816 B
    __shared__ __align__(16) u16 s_cw[4][64 * CW_STR];  // 34,816 B
    __shared__ __align__(16) u32 s_ws[4 * 32];          //    512 B
    __shared__ __align__(16) float s_msum[8][16];       //    512 B
    // total 149,504 B -> 1 block/CU

    const int t = threadIdx.x;
    const int w = t >> 6, l = t & 63;
    const int ml = l & 15, q = l >> 4;
    const int b = blockIdx.x;   // molecule 0..63

    // ================= Phase 0: stage c, waT (all heads), wpT (all heads), ws =========
    {   // waT[n][ho][h] = f16(Wa_pair[h][4*ho+n]); coalesced reads of 2 rows per thread
        const int hp = t >> 4;            // h-pair 0..31
        const int cc = (t & 15) * 16;     // c-chunk base
        const float* r0p = Wa_pair + (2 * hp) * 256 + cc;
        const float* r1p = Wa_pair + (2 * hp + 1) * 256 + cc;
        #pragma unroll
        for (int v = 0; v < 4; ++v) {
            const f32x4 x0 = *(const f32x4*)(r0p + v * 4);
            const f32x4 x1 = *(const f32x4*)(r1p + v * 4);
            #pragma unroll
            for (int e = 0; e < 4; ++e) {
                const int c = cc + v * 4 + e;
                const int n = c & 3, ho = c >> 2;
                *(u32*)&s_u.p1.wa[n][ho * WA_STR + 2 * hp] = pk2(x0[e], x1[e]);
            }
        }
    }
    {   // wpT[n][o][h] = f16(W_proj[4h+n][o]); h-pairs packed, coalesced row reads
        const int n = t >> 7, r = t & 127;
        const int hh = r >> 2, o0 = (r & 3) * 16;
        const float* c0p = W_proj + (8 * hh + n) * 64 + o0;
        const float* c1p = W_proj + (8 * hh + 4 + n) * 64 + o0;
        #pragma unroll
        for (int v = 0; v < 4; ++v) {
            const f32x4 x0 = *(const f32x4*)(c0p + v * 4);
            const f32x4 x1 = *(const f32x4*)(c1p + v * 4);
            #pragma unroll
            for (int e = 0; e < 4; ++e) {
                const int o = o0 + v * 4 + e;
                *(u32*)&s_u.p1.wp[n][o * WP_STR + 2 * hh] = pk2(x0[e], x1[e]);
            }
        }
    }
    if (t < 256) {   // c rows -> cb [j][h] (f16 packed)
        const int jp = (t & 31) * 2;
        const int pp = t >> 5;           // h-octant 0..7
        const int r0 = scope[b * 64 + jp];
        const int r1 = scope[b * 64 + jp + 1];
        const f32x4 a0 = *(const f32x4*)(inputs + (size_t)r0 * 64 + pp * 8);
        const f32x4 a1 = *(const f32x4*)(inputs + (size_t)r0 * 64 + pp * 8 + 4);
        const f32x4 b0 = *(const f32x4*)(inputs + (size_t)r1 * 64 + pp * 8);
        const f32x4 b1 = *(const f32x4*)(inputs + (size_t)r1 * 64 + pp * 8 + 4);
        *(uint4*)&s_cb[jp * CB_STR + pp * 8] =
            make_uint4(pk2(a0[0], a0[1]), pk2(a0[2], a0[3]), pk2(a1[0], a1[1]), pk2(a1[2], a1[3]));
        *(uint4*)&s_cb[(jp + 1) * CB_STR + pp * 8] =
            make_uint4(pk2(b0[0], b0[1]), pk2(b0[2], b0[3]), pk2(b1[0], b1[1]), pk2(b1[2], b1[3]));
    }
    if (t < 128) {   // ws[n][hh] packed pairs along ho
        const int n = t >> 5, hh = t & 31;
        s_ws[n * 32 + hh] = pk2(Wa_score[(2 * hh) * 4 + n], Wa_score[(2 * hh + 1) * 4 + n]);
    }
    if (b == 0 && t < 64) out_flat[t] = 0.f;   // pad row 0
    __syncthreads();

    // ========== Phase 1: waves 0-3: P_n = waT_n @ c^T ; waves 4-7: cw_n = c @ Wp_n ====
    if (w < 4) {
        const int n = w;   // head
        f32x4 D[4][4];
        #pragma unroll
        for (int mt = 0; mt < 4; ++mt)
            #pragma unroll
            for (int jt = 0; jt < 4; ++jt) D[mt][jt] = (f32x4)0.f;
        #pragma unroll
        for (int ks = 0; ks < 2; ++ks) {
            h8 bfj[4];
            #pragma unroll
            for (int jt = 0; jt < 4; ++jt)
                bfj[jt] = __builtin_bit_cast(h8,
                    *(const uint4*)&s_cb[(jt * 16 + ml) * CB_STR + ks * 32 + q * 8]);
            #pragma unroll
            for (int mt = 0; mt < 4; ++mt) {
                const uint2 x0 = *(const uint2*)&s_u.p1.wa[n][(mt * 16 + ml) * WA_STR + ks * 32 + q * 8];
                const uint2 x1 = *(const uint2*)&s_u.p1.wa[n][(mt * 16 + ml) * WA_STR + ks * 32 + q * 8 + 4];
                const h8 af = frag4(x0.x, x0.y, x1.x, x1.y);
                #pragma unroll
                for (int jt = 0; jt < 4; ++jt)
                    D[mt][jt] = __builtin_amdgcn_mfma_f32_16x16x32_f16(af, bfj[jt], D[mt][jt], 0, 0, 0);
            }
        }
        // store P as [atom j][ho]: rows ho = mt*16+q*4+r packed in pairs
        #pragma unroll
        for (int mt = 0; mt < 4; ++mt)
            #pragma unroll
            for (int jt = 0; jt < 4; ++jt) {
                const int j = jt * 16 + ml;
                *(uint2*)&s_p[n][j * P_STR + mt * 16 + q * 4] =
                    make_uint2(pk2(D[mt][jt][0], D[mt][jt][1]), pk2(D[mt][jt][2], D[mt][jt][3]));
            }
    } else {
        const int n = w - 4;   // head
        f32x4 D[4][4];
        #pragma unroll
        for (int mt = 0; mt < 4; ++mt)
            #pragma unroll
            for (int ot = 0; ot < 4; ++ot) D[mt][ot] = (f32x4)0.f;
        #pragma unroll
        for (int ks = 0; ks < 2; ++ks) {
            h8 afm[4];
            #pragma unroll
            for (int mt = 0; mt < 4; ++mt)
                afm[mt] = __builtin_bit_cast(h8,
                    *(const uint4*)&s_cb[(mt * 16 + ml) * CB_STR + ks * 32 + q * 8]);
            #pragma unroll
            for (int ot = 0; ot < 4; ++ot) {
                const uint2 y0 = *(const uint2*)&s_u.p1.wp[n][(ot * 16 + ml) * WP_STR + ks * 32 + q * 8];
                const uint2 y1 = *(const uint2*)&s_u.p1.wp[n][(ot * 16 + ml) * WP_STR + ks * 32 + q * 8 + 4];
                const h8 bf = frag4(y0.x, y0.y, y1.x, y1.y);
                #pragma unroll
                for (int mt = 0; mt < 4; ++mt)
                    D[mt][ot] = __builtin_amdgcn_mfma_f32_16x16x32_f16(afm[mt], bf, D[mt][ot], 0, 0, 0);
            }
        }
        // store cw^T as [o][j]: rows j = mt*16+q*4+r packed in pairs
        #pragma unroll
        for (int mt = 0; mt < 4; ++mt)
            #pragma unroll
            for (int ot = 0; ot < 4; ++ot) {
                const int o = ot * 16 + ml;
                *(uint2*)&s_cw[n][o * CW_STR + mt * 16 + q * 4] =
                    make_uint2(pk2(D[mt][ot][0], D[mt][ot][1]), pk2(D[mt][ot][2], D[mt][ot][3]));
            }
    }
    __syncthreads();

    // ================= Phase 2: scores; wave = (n, i-half), lane = j =================
    {
        const int n = w & 3, ih = w >> 2;
        u32 pj_u[32];
        #pragma unroll
        for (int k = 0; k < 16; ++k) {
            const uint2 vv = *(const uint2*)&s_p[n][l * P_STR + k * 4];
            pj_u[2 * k] = vv.x; pj_u[2 * k + 1] = vv.y;
        }
        u32 ws_u[32];
        #pragma unroll
        for (int k = 0; k < 8; ++k) {
            const uint4 vv = *(const uint4*)&s_ws[n * 32 + k * 4];
            ws_u[4 * k] = vv.x; ws_u[4 * k + 1] = vv.y;
            ws_u[4 * k + 2] = vv.z; ws_u[4 * k + 3] = vv.w;
        }
        const h2 zero2 = {(_Float16)0.f, (_Float16)0.f};
        #pragma unroll 4
        for (int ii = 0; ii < 32; ++ii) {
            const int i = ih * 32 + ii;
            const u16* pir = &s_p[n][i * P_STR];   // uniform across lanes -> LDS broadcast
            float s0 = 0.f, s1 = 0.f;
            #pragma unroll
            for (int c8 = 0; c8 < 8; ++c8) {
                const uint2 u0 = *(const uint2*)&pir[c8 * 8];
                const uint2 u1 = *(const uint2*)&pir[c8 * 8 + 4];
                const u32 pe[4] = {u0.x, u0.y, u1.x, u1.y};
                #pragma unroll
                for (int e = 0; e < 4; ++e) {
                    const h2 pi2 = __builtin_bit_cast(h2, pe[e]);
                    const h2 pj2 = __builtin_bit_cast(h2, pj_u[c8 * 4 + e]);
                    h2 tv = pi2 + pj2;                         // v_pk_add_f16
                    tv = __builtin_elementwise_max(tv, zero2); // v_pk_max_f16
                    if (e & 1)
                        s1 = __builtin_amdgcn_fdot2(tv,
                                __builtin_bit_cast(h2, ws_u[c8 * 4 + e]), s1, false);
                    else
                        s0 = __builtin_amdgcn_fdot2(tv,
                                __builtin_bit_cast(h2, ws_u[c8 * 4 + e]), s0, false);
                }
            }
            const float s = s0 + s1;
            const float a = 1.f / (1.f + __expf(-s));
            const _Float16 ah = (_Float16)a;
            s_u.ab[i * ABF_STR + n * 64 + l] = __builtin_bit_cast(u16, ah);
        }
    }
    __syncthreads();

    // ===== Phase 3: out = ab @ cwflat (M=64 i, N=64 o, K=256 c=(n,j)); plain stores ====
    {
        const int nt = w >> 1, mh = w & 1;
        f32x4 D3[2];
        D3[0] = (f32x4)0.f; D3[1] = (f32x4)0.f;
        #pragma unroll
        for (int ks = 0; ks < 8; ++ks) {
            const int n = ks >> 1;
            const uint2 y0 = *(const uint2*)&s_cw[n][(nt * 16 + ml) * CW_STR + (ks & 1) * 32 + q * 8];
            const uint2 y1 = *(const uint2*)&s_cw[n][(nt * 16 + ml) * CW_STR + (ks & 1) * 32 + q * 8 + 4];
            const h8 bf = frag4(y0.x, y0.y, y1.x, y1.y);
            #pragma unroll
            for (int mtl = 0; mtl < 2; ++mtl) {
                const int mt = mh * 2 + mtl;
                const h8 af = __builtin_bit_cast(h8,
                    *(const uint4*)&s_u.ab[(mt * 16 + ml) * ABF_STR + ks * 32 + q * 8]);
                D3[mtl] = __builtin_amdgcn_mfma_f32_16x16x32_f16(af, bf, D3[mtl], 0, 0, 0);
            }
        }
        const int o = nt * 16 + ml;
        float colsum = 0.f;
        #pragma unroll
        for (int mtl = 0; mtl < 2; ++mtl)
            #pragma unroll
            for (int r = 0; r < 4; ++r) {
                const int i = (mh * 2 + mtl) * 16 + q * 4 + r;
                const int row = scope[b * 64 + i];
                if (row > 0) out_flat[(size_t)row * 64 + o] = D3[mtl][r];
                colsum += D3[mtl][r];   // pad i rows DO contribute to out_mol (matches ref)
            }
        colsum += __shfl_xor(colsum, 16, 64);
        colsum += __shfl_xor(colsum, 32, 64);
        if (l < 16) s_msum[w][ml] = colsum;
    }
    __syncthreads();
    if (t < 64)
        out_mol[b * 64 + t] = s_msum[2 * (t >> 4)][t & 15] + s_msum[2 * (t >> 4) + 1][t & 15];
}

extern "C" void kernel_launch(void* const* d_in, const int* in_sizes, int n_in,
                              void* d_out, int out_size, void* d_ws, size_t ws_size,
                              hipStream_t stream) {
    const float* inputs   = (const float*)d_in[0];
    const int*   scope    = (const int*)d_in[1];
    // d_in[2] = scope_rev (unused: flat row index == scope value)
    const float* Wa_pair  = (const float*)d_in[3];
    const float* Wa_score = (const float*)d_in[4];
    const float* W_proj   = (const float*)d_in[5];
    float* out = (float*)d_out;

    // Single dispatch: every output element is computed by exactly one block -> no memset.
    dim3 grid(64);   // one block per molecule; 512 thr; 149.5 KB LDS
    atom_attn<<<grid, 512, 0, stream>>>(inputs, scope, Wa_pair, Wa_score,
                                        W_proj, out, out + 64 * 64);
}

// Round 4
// 74.030 us; speedup vs baseline: 1.1467x; 1.1467x over previous
//
#include <hip/hip_runtime.h>
#include <stdint.h>

typedef _Float16 h2 __attribute__((ext_vector_type(2)));
typedef _Float16 h8 __attribute__((ext_vector_type(8)));
typedef float f32x4 __attribute__((ext_vector_type(4)));
typedef unsigned int u32;
typedef unsigned short u16;

// LDS strides (elements of the buffer's type)
#define CB_STR  72    // cb   [j=64][h]      u16 ; 144B rows (uint4 reads)
#define WA_STR  68    // waT  [n][ho=64][h]  u16 ; 136B rows (uint2 reads)
#define WP_STR  68    // wpT  [n][o=64][h]   u16 ; 136B rows
#define P_STR   68    // P    [n][atom][ho]  u16 ; 136B rows
#define CW_STR  68    // cwT  [n][o=64][j]   u16 ; 136B rows
#define ABF_STR 264   // ab   [i=16][c=(n,j)=256] u16 ; 528B rows (uint4 reads)

__device__ __forceinline__ u32 pk2(float a, float b) {
    return __builtin_bit_cast(u32, __builtin_amdgcn_cvt_pkrtz(a, b));
}
__device__ __forceinline__ h8 frag4(u32 a, u32 b, u32 c, u32 d) {
    return __builtin_bit_cast(h8, make_uint4(a, b, c, d));
}

// grid = (i-quarter bx, molecule b) -> 256 blocks (full machine).
// Each block: full P & cw (heads split across waves), scores+output for its 16 i-rows.
// out_flat single-writer (plain stores); only out_mol accumulates via atomics (16.6 KB memset).
union SMemU {
    struct { u16 wa[4][64 * WA_STR]; u16 wp[4][64 * WP_STR]; } p1;  // 69,632 B (phase 0-1)
    u16 ab[16 * ABF_STR];                                            //  8,448 B (phase 2-3)
};

__global__ __launch_bounds__(512, 1) void atom_attn(
    const float* __restrict__ inputs,
    const int*   __restrict__ scope,
    const float* __restrict__ Wa_pair,
    const float* __restrict__ Wa_score,
    const float* __restrict__ W_proj,
    float* __restrict__ out_mol,    // [64][64]
    float* __restrict__ out_flat)   // [N+1][64]
{
    __shared__ __align__(16) SMemU s_u;                 // 69,632 B
    __shared__ __align__(16) u16 s_cb[64 * CB_STR];     //  9,216 B
    __shared__ __align__(16) u16 s_p [4][64 * P_STR];   // 34,816 B
    __shared__ __align__(16) u16 s_cw[4][64 * CW_STR];  // 34,816 B
    __shared__ __align__(16) u32 s_ws[4 * 32];          //    512 B
    // total 148,992 B -> 1 block/CU

    const int t = threadIdx.x;
    const int w = t >> 6, l = t & 63;
    const int ml = l & 15, q = l >> 4;
    const int bx = blockIdx.x;  // i-quarter 0..3
    const int b  = blockIdx.y;  // molecule 0..63

    // ================= Phase 0: stage c, waT (all heads), wpT (all heads), ws =========
    {   // waT[n][ho][h] = f16(Wa_pair[h][4*ho+n]); coalesced reads of 2 rows per thread
        const int hp = t >> 4;            // h-pair 0..31
        const int cc = (t & 15) * 16;     // c-chunk base
        const float* r0p = Wa_pair + (2 * hp) * 256 + cc;
        const float* r1p = Wa_pair + (2 * hp + 1) * 256 + cc;
        #pragma unroll
        for (int v = 0; v < 4; ++v) {
            const f32x4 x0 = *(const f32x4*)(r0p + v * 4);
            const f32x4 x1 = *(const f32x4*)(r1p + v * 4);
            #pragma unroll
            for (int e = 0; e < 4; ++e) {
                const int c = cc + v * 4 + e;
                const int n = c & 3, ho = c >> 2;
                *(u32*)&s_u.p1.wa[n][ho * WA_STR + 2 * hp] = pk2(x0[e], x1[e]);
            }
        }
    }
    {   // wpT[n][o][h] = f16(W_proj[4h+n][o]); h-pairs packed, coalesced row reads
        const int n = t >> 7, r = t & 127;
        const int hh = r >> 2, o0 = (r & 3) * 16;
        const float* c0p = W_proj + (8 * hh + n) * 64 + o0;
        const float* c1p = W_proj + (8 * hh + 4 + n) * 64 + o0;
        #pragma unroll
        for (int v = 0; v < 4; ++v) {
            const f32x4 x0 = *(const f32x4*)(c0p + v * 4);
            const f32x4 x1 = *(const f32x4*)(c1p + v * 4);
            #pragma unroll
            for (int e = 0; e < 4; ++e) {
                const int o = o0 + v * 4 + e;
                *(u32*)&s_u.p1.wp[n][o * WP_STR + 2 * hh] = pk2(x0[e], x1[e]);
            }
        }
    }
    if (t < 256) {   // c rows -> cb [j][h] (f16 packed)
        const int jp = (t & 31) * 2;
        const int pp = t >> 5;           // h-octant 0..7
        const int r0 = scope[b * 64 + jp];
        const int r1 = scope[b * 64 + jp + 1];
        const f32x4 a0 = *(const f32x4*)(inputs + (size_t)r0 * 64 + pp * 8);
        const f32x4 a1 = *(const f32x4*)(inputs + (size_t)r0 * 64 + pp * 8 + 4);
        const f32x4 b0 = *(const f32x4*)(inputs + (size_t)r1 * 64 + pp * 8);
        const f32x4 b1 = *(const f32x4*)(inputs + (size_t)r1 * 64 + pp * 8 + 4);
        *(uint4*)&s_cb[jp * CB_STR + pp * 8] =
            make_uint4(pk2(a0[0], a0[1]), pk2(a0[2], a0[3]), pk2(a1[0], a1[1]), pk2(a1[2], a1[3]));
        *(uint4*)&s_cb[(jp + 1) * CB_STR + pp * 8] =
            make_uint4(pk2(b0[0], b0[1]), pk2(b0[2], b0[3]), pk2(b1[0], b1[1]), pk2(b1[2], b1[3]));
    }
    if (t < 128) {   // ws[n][hh] packed pairs along ho
        const int n = t >> 5, hh = t & 31;
        s_ws[n * 32 + hh] = pk2(Wa_score[(2 * hh) * 4 + n], Wa_score[(2 * hh + 1) * 4 + n]);
    }
    __syncthreads();

    // ========== Phase 1: waves 0-3: P_n = waT_n @ c^T ; waves 4-7: cw_n = c @ Wp_n ====
    if (w < 4) {
        const int n = w;   // head
        f32x4 D[4][4];
        #pragma unroll
        for (int mt = 0; mt < 4; ++mt)
            #pragma unroll
            for (int jt = 0; jt < 4; ++jt) D[mt][jt] = (f32x4)0.f;
        #pragma unroll
        for (int ks = 0; ks < 2; ++ks) {
            h8 bfj[4];
            #pragma unroll
            for (int jt = 0; jt < 4; ++jt)
                bfj[jt] = __builtin_bit_cast(h8,
                    *(const uint4*)&s_cb[(jt * 16 + ml) * CB_STR + ks * 32 + q * 8]);
            #pragma unroll
            for (int mt = 0; mt < 4; ++mt) {
                const uint2 x0 = *(const uint2*)&s_u.p1.wa[n][(mt * 16 + ml) * WA_STR + ks * 32 + q * 8];
                const uint2 x1 = *(const uint2*)&s_u.p1.wa[n][(mt * 16 + ml) * WA_STR + ks * 32 + q * 8 + 4];
                const h8 af = frag4(x0.x, x0.y, x1.x, x1.y);
                #pragma unroll
                for (int jt = 0; jt < 4; ++jt)
                    D[mt][jt] = __builtin_amdgcn_mfma_f32_16x16x32_f16(af, bfj[jt], D[mt][jt], 0, 0, 0);
            }
        }
        // store P as [atom j][ho]: rows ho = mt*16+q*4+r packed in pairs
        #pragma unroll
        for (int mt = 0; mt < 4; ++mt)
            #pragma unroll
            for (int jt = 0; jt < 4; ++jt) {
                const int j = jt * 16 + ml;
                *(uint2*)&s_p[n][j * P_STR + mt * 16 + q * 4] =
                    make_uint2(pk2(D[mt][jt][0], D[mt][jt][1]), pk2(D[mt][jt][2], D[mt][jt][3]));
            }
    } else {
        const int n = w - 4;   // head
        f32x4 D[4][4];
        #pragma unroll
        for (int mt = 0; mt < 4; ++mt)
            #pragma unroll
            for (int ot = 0; ot < 4; ++ot) D[mt][ot] = (f32x4)0.f;
        #pragma unroll
        for (int ks = 0; ks < 2; ++ks) {
            h8 afm[4];
            #pragma unroll
            for (int mt = 0; mt < 4; ++mt)
                afm[mt] = __builtin_bit_cast(h8,
                    *(const uint4*)&s_cb[(mt * 16 + ml) * CB_STR + ks * 32 + q * 8]);
            #pragma unroll
            for (int ot = 0; ot < 4; ++ot) {
                const uint2 y0 = *(const uint2*)&s_u.p1.wp[n][(ot * 16 + ml) * WP_STR + ks * 32 + q * 8];
                const uint2 y1 = *(const uint2*)&s_u.p1.wp[n][(ot * 16 + ml) * WP_STR + ks * 32 + q * 8 + 4];
                const h8 bf = frag4(y0.x, y0.y, y1.x, y1.y);
                #pragma unroll
                for (int mt = 0; mt < 4; ++mt)
                    D[mt][ot] = __builtin_amdgcn_mfma_f32_16x16x32_f16(afm[mt], bf, D[mt][ot], 0, 0, 0);
            }
        }
        // store cw^T as [o][j]: rows j = mt*16+q*4+r packed in pairs
        #pragma unroll
        for (int mt = 0; mt < 4; ++mt)
            #pragma unroll
            for (int ot = 0; ot < 4; ++ot) {
                const int o = ot * 16 + ml;
                *(uint2*)&s_cw[n][o * CW_STR + mt * 16 + q * 4] =
                    make_uint2(pk2(D[mt][ot][0], D[mt][ot][1]), pk2(D[mt][ot][2], D[mt][ot][3]));
            }
    }
    __syncthreads();

    // ===== Phase 2: scores for this block's 16 i-rows; wave = (n, i-half), lane = j ====
    {
        const int n = w & 3, ih = w >> 2;
        u32 pj_u[32];
        #pragma unroll
        for (int k = 0; k < 16; ++k) {
            const uint2 vv = *(const uint2*)&s_p[n][l * P_STR + k * 4];
            pj_u[2 * k] = vv.x; pj_u[2 * k + 1] = vv.y;
        }
        u32 ws_u[32];
        #pragma unroll
        for (int k = 0; k < 8; ++k) {
            const uint4 vv = *(const uint4*)&s_ws[n * 32 + k * 4];
            ws_u[4 * k] = vv.x; ws_u[4 * k + 1] = vv.y;
            ws_u[4 * k + 2] = vv.z; ws_u[4 * k + 3] = vv.w;
        }
        const h2 zero2 = {(_Float16)0.f, (_Float16)0.f};
        #pragma unroll
        for (int ii = 0; ii < 8; ++ii) {
            const int i_loc = ih * 8 + ii;
            const int i = bx * 16 + i_loc;
            const u16* pir = &s_p[n][i * P_STR];   // uniform across lanes -> LDS broadcast
            float s0 = 0.f, s1 = 0.f;
            #pragma unroll
            for (int c8 = 0; c8 < 8; ++c8) {
                const uint2 u0 = *(const uint2*)&pir[c8 * 8];
                const uint2 u1 = *(const uint2*)&pir[c8 * 8 + 4];
                const u32 pe[4] = {u0.x, u0.y, u1.x, u1.y};
                #pragma unroll
                for (int e = 0; e < 4; ++e) {
                    const h2 pi2 = __builtin_bit_cast(h2, pe[e]);
                    const h2 pj2 = __builtin_bit_cast(h2, pj_u[c8 * 4 + e]);
                    h2 tv = pi2 + pj2;                         // v_pk_add_f16
                    tv = __builtin_elementwise_max(tv, zero2); // v_pk_max_f16
                    if (e & 1)
                        s1 = __builtin_amdgcn_fdot2(tv,
                                __builtin_bit_cast(h2, ws_u[c8 * 4 + e]), s1, false);
                    else
                        s0 = __builtin_amdgcn_fdot2(tv,
                                __builtin_bit_cast(h2, ws_u[c8 * 4 + e]), s0, false);
                }
            }
            const float s = s0 + s1;
            const float a = 1.f / (1.f + __expf(-s));
            const _Float16 ah = (_Float16)a;
            s_u.ab[i_loc * ABF_STR + n * 64 + l] = __builtin_bit_cast(u16, ah);
        }
    }
    __syncthreads();

    // ===== Phase 3: out[16 i][64 o] = ab @ cwflat (K=256 c=(n,j)); waves 0-3, plain stores
    if (w < 4) {
        f32x4 D = (f32x4)0.f;
        #pragma unroll
        for (int ks = 0; ks < 8; ++ks) {
            const int n = ks >> 1;
            const h8 af = __builtin_bit_cast(h8,
                *(const uint4*)&s_u.ab[ml * ABF_STR + ks * 32 + q * 8]);
            const uint2 y0 = *(const uint2*)&s_cw[n][(w * 16 + ml) * CW_STR + (ks & 1) * 32 + q * 8];
            const uint2 y1 = *(const uint2*)&s_cw[n][(w * 16 + ml) * CW_STR + (ks & 1) * 32 + q * 8 + 4];
            const h8 bf = frag4(y0.x, y0.y, y1.x, y1.y);
            D = __builtin_amdgcn_mfma_f32_16x16x32_f16(af, bf, D, 0, 0, 0);
        }
        const int o = w * 16 + ml;
        float colsum = 0.f;
        #pragma unroll
        for (int r = 0; r < 4; ++r) {
            const int i_loc = q * 4 + r;
            const int row = scope[b * 64 + bx * 16 + i_loc];
            if (row > 0) out_flat[(size_t)row * 64 + o] = D[r];   // single writer
            colsum += D[r];   // pad i rows DO contribute to out_mol (matches reference)
        }
        colsum += __shfl_xor(colsum, 16, 64);
        colsum += __shfl_xor(colsum, 32, 64);
        if (l < 16) atomicAdd(out_mol + b * 64 + o, colsum);   // 4 contenders (i-quarters)
    }
}

extern "C" void kernel_launch(void* const* d_in, const int* in_sizes, int n_in,
                              void* d_out, int out_size, void* d_ws, size_t ws_size,
                              hipStream_t stream) {
    const float* inputs   = (const float*)d_in[0];
    const int*   scope    = (const int*)d_in[1];
    // d_in[2] = scope_rev (unused: flat row index == scope value)
    const float* Wa_pair  = (const float*)d_in[3];
    const float* Wa_score = (const float*)d_in[4];
    const float* W_proj   = (const float*)d_in[5];
    float* out = (float*)d_out;

    // zero only what isn't single-writer: out_mol [64*64] + flat pad row 0 [64] = 16.6 KB
    (void)hipMemsetAsync(d_out, 0, (64 * 64 + 64) * sizeof(float), stream);

    // (i-quarter, molecule): 256 blocks x 512 thr; 149 KB LDS -> 1 block/CU
    dim3 grid(4, 64);
    atom_attn<<<grid, 512, 0, stream>>>(inputs, scope, Wa_pair, Wa_score,
                                        W_proj, out, out + 64 * 64);
}